// Round 2
// baseline (637.460 us; speedup 1.0000x reference)
//
#include <hip/hip_runtime.h>
#include <hip/hip_cooperative_groups.h>
#include <math.h>

namespace cg = cooperative_groups;

// SE layer: B=16, C=256, H=W=128. Only batch 0 is gated (reference uses s[0]).
#define HW       16384          // 128*128
#define CCH      256
#define HID      16
#define NBLK     1024           // 4 blocks/CU on 256 CUs -> co-resident
#define NTHR     256
#define NTHREADS (NBLK * NTHR)  // 262144
#define B0_VEC   1048576        // float4s in batch 0: 256 * 4096
#define TOT_VEC  16777216       // float4s total:     16 * 256 * 4096

// One persistent cooperative kernel:
//  phase 1: per-block partial sums of batch 0 (block b owns float4s
//           [b*1024, (b+1)*1024) -- exactly 1/4 of channel b>>2)
//  sync
//  phase 2: block 0 computes MLP gates; ALL blocks copy batches 1..15
//  sync
//  phase 3: all blocks scale their batch-0 chunk by gate[channel]
__launch_bounds__(NTHR, 4)
__global__ void se_fused(const float* __restrict__ x,
                         const float* __restrict__ w1, const float* __restrict__ b1,
                         const float* __restrict__ w2, const float* __restrict__ b2,
                         float* __restrict__ out, float* __restrict__ ws) {
    const int t = threadIdx.x;
    const int b = blockIdx.x;
    const float4* __restrict__ x4 = (const float4*)x;
    float4* __restrict__ o4 = (float4*)out;

    __shared__ float wsum[4];
    __shared__ float ysh[CCH];
    __shared__ float h[HID];

    // ---- Phase 1: partial sum over this block's 1024-float4 chunk of batch 0
    const size_t chunk = (size_t)b * 1024;
    float sum = 0.f;
    #pragma unroll
    for (int k = 0; k < 4; ++k) {
        float4 v = x4[chunk + (size_t)k * 256 + t];
        sum += (v.x + v.y) + (v.z + v.w);
    }
    #pragma unroll
    for (int off = 32; off > 0; off >>= 1)
        sum += __shfl_down(sum, off, 64);
    if ((t & 63) == 0) wsum[t >> 6] = sum;
    __syncthreads();
    if (t == 0) ws[b] = (wsum[0] + wsum[1]) + (wsum[2] + wsum[3]);

    cg::this_grid().sync();

    // ---- Phase 2a: block 0 computes the MLP -> gates in ws[2048..2303]
    if (b == 0) {
        float yv = (ws[4 * t] + ws[4 * t + 1] + ws[4 * t + 2] + ws[4 * t + 3])
                   * (1.0f / (float)HW);
        ysh[t] = yv;
        __syncthreads();
        if (t < HID) {
            float acc = b1[t];
            const float* wr = w1 + t * CCH;
            #pragma unroll 8
            for (int c = 0; c < CCH; ++c) acc = fmaf(ysh[c], wr[c], acc);
            h[t] = fmaxf(acc, 0.f);
        }
        __syncthreads();
        float acc = b2[t];
        const float* wr2 = w2 + t * HID;
        #pragma unroll
        for (int j = 0; j < HID; ++j) acc = fmaf(h[j], wr2[j], acc);
        ws[2048 + t] = 1.0f / (1.0f + __expf(-acc));
    }

    // ---- Phase 2b: everyone copies batches 1..15 (independent of gates)
    // 15,728,640 float4s / 262,144 threads = exactly 60 iterations
    const int tid = b * NTHR + t;
    for (size_t i = (size_t)B0_VEC + tid; i < TOT_VEC; i += NTHREADS)
        o4[i] = x4[i];

    cg::this_grid().sync();

    // ---- Phase 3: scale this block's batch-0 chunk (L2-warm from phase 1)
    const float g = ws[2048 + (b >> 2)];   // channel = b/4, uniform per block
    #pragma unroll
    for (int k = 0; k < 4; ++k) {
        const size_t i = chunk + (size_t)k * 256 + t;
        float4 v = x4[i];
        v.x *= g; v.y *= g; v.z *= g; v.w *= g;
        o4[i] = v;
    }
}

extern "C" void kernel_launch(void* const* d_in, const int* in_sizes, int n_in,
                              void* d_out, int out_size, void* d_ws, size_t ws_size,
                              hipStream_t stream) {
    const float* x  = (const float*)d_in[0];
    const float* w1 = (const float*)d_in[1];
    const float* b1 = (const float*)d_in[2];
    const float* w2 = (const float*)d_in[3];
    const float* b2 = (const float*)d_in[4];
    float* out = (float*)d_out;
    float* ws  = (float*)d_ws;

    void* args[] = {(void*)&x, (void*)&w1, (void*)&b1, (void*)&w2, (void*)&b2,
                    (void*)&out, (void*)&ws};
    hipLaunchCooperativeKernel((void*)se_fused, dim3(NBLK), dim3(NTHR),
                               args, 0, stream);
}